// Round 5
// baseline (10584.934 us; speedup 1.0000x reference)
//
#include <hip/hip_runtime.h>
#include <stdint.h>
#include <math.h>

// ---------------------------------------------------------------------------
// GatedMultiplicativeSelfAttention: B=8, S=2048, D=512, H=512
// Pipeline:
//  1) rin[:, :512] = bf16(x)
//  2) xT = bf16(x^T) per batch
//  3) Wx = x @ W^T                    (bf16 MFMA GEMM)
//  4) per batch: s = Wx @ x^T ; softmax(mask diag) in-place (bf16) ; c = a @ x
//  5) ring = rin * sigmoid(rin @ Wg^T)
//  6) xw_f/xw_b = ring @ Wih^T + bih  (bf16)
//  7) persistent bidirectional GRU scan, tagged-h MALL exchange (no flags)
//  8) out = x + hcat @ Wp^T + bp
// ---------------------------------------------------------------------------

typedef __attribute__((ext_vector_type(8))) short bfx8;
typedef __attribute__((ext_vector_type(4))) float fx4;

__device__ __forceinline__ float bf2f(unsigned short u) {
  union { unsigned int i; float f; } v; v.i = ((unsigned int)u) << 16; return v.f;
}
__device__ __forceinline__ unsigned short f2bf(float f) {
  union { float f; unsigned int i; } v; v.f = f;
  unsigned int x = v.i;
  return (unsigned short)((x + 0x7fffu + ((x >> 16) & 1u)) >> 16);
}

// ---------------- generic BT GEMM: C[M,N] = A[M,K] * B[N,K]^T ---------------
#define EP_BF16 0
#define EP_F32 1
#define EP_GATE 2
#define EP_RESID 3
#define EP_BIASBF 4

template <int EP>
__global__ __launch_bounds__(256)
void gemm_bt(const unsigned short* __restrict__ A, int lda,
             const unsigned short* __restrict__ B, int ldb,
             void* __restrict__ Cp, int ldc, int K,
             const void* __restrict__ P, const float* __restrict__ bias) {
  __shared__ __attribute__((aligned(16))) unsigned short As[128 * 64];
  __shared__ __attribute__((aligned(16))) unsigned short Bs[128 * 64];
  const int tid = threadIdx.x;
  const int w = tid >> 6, l = tid & 63;
  const int bm = blockIdx.y << 7, bn = blockIdx.x << 7;
  const int wm = (w >> 1) << 6, wn = (w & 1) << 6;
  const int fr = l & 15, fk = (l >> 4) << 3;
  fx4 zero4 = {0.f, 0.f, 0.f, 0.f};
  fx4 acc[4][4];
#pragma unroll
  for (int i = 0; i < 4; ++i)
#pragma unroll
    for (int j = 0; j < 4; ++j) acc[i][j] = zero4;

  for (int k0 = 0; k0 < K; k0 += 64) {
#pragma unroll
    for (int c = 0; c < 4; ++c) {
      int e = (tid + (c << 8)) << 3;
      int r = e >> 6, cc = e & 63;
      *(uint4*)&As[e] = *(const uint4*)&A[(size_t)(bm + r) * lda + k0 + cc];
      *(uint4*)&Bs[e] = *(const uint4*)&B[(size_t)(bn + r) * ldb + k0 + cc];
    }
    __syncthreads();
#pragma unroll
    for (int kk = 0; kk < 64; kk += 32) {
      bfx8 a[4], b[4];
#pragma unroll
      for (int m = 0; m < 4; ++m) a[m] = *(const bfx8*)&As[(wm + (m << 4) + fr) * 64 + kk + fk];
#pragma unroll
      for (int n = 0; n < 4; ++n) b[n] = *(const bfx8*)&Bs[(wn + (n << 4) + fr) * 64 + kk + fk];
#pragma unroll
      for (int m = 0; m < 4; ++m)
#pragma unroll
        for (int n = 0; n < 4; ++n)
          acc[m][n] = __builtin_amdgcn_mfma_f32_16x16x32_bf16(a[m], b[n], acc[m][n], 0, 0, 0);
    }
    __syncthreads();
  }
  const int er = (l >> 4) << 2, ec = l & 15;
#pragma unroll
  for (int m = 0; m < 4; ++m)
#pragma unroll
    for (int n = 0; n < 4; ++n)
#pragma unroll
      for (int i = 0; i < 4; ++i) {
        int gr = bm + wm + (m << 4) + er + i;
        int gc = bn + wn + (n << 4) + ec;
        float v = acc[m][n][i];
        size_t idx = (size_t)gr * ldc + gc;
        if constexpr (EP == EP_F32) {
          ((float*)Cp)[idx] = v;
        } else if constexpr (EP == EP_BF16) {
          ((unsigned short*)Cp)[idx] = f2bf(v);
        } else if constexpr (EP == EP_BIASBF) {
          ((unsigned short*)Cp)[idx] = f2bf(v + bias[gc]);
        } else if constexpr (EP == EP_GATE) {
          float rv = bf2f(((const unsigned short*)P)[idx]);
          float sg = 1.f / (1.f + __expf(-v));
          ((unsigned short*)Cp)[idx] = f2bf(rv * sg);
        } else {  // EP_RESID
          float xv = ((const float*)P)[idx];
          ((float*)Cp)[idx] = v + xv + bias[gc];
        }
      }
}

// ---------------- small prep kernels ----------------------------------------
__global__ __launch_bounds__(256)
void cast_w_kernel(const float* __restrict__ in, unsigned short* __restrict__ out, int n) {
  int e = (blockIdx.x * 256 + threadIdx.x) * 4;
  if (e >= n) return;
  float4 v = *(const float4*)&in[e];
  ushort4 u;
  u.x = f2bf(v.x); u.y = f2bf(v.y); u.z = f2bf(v.z); u.w = f2bf(v.w);
  *(ushort4*)&out[e] = u;
}

__global__ __launch_bounds__(256)
void cast_x_kernel(const float* __restrict__ x, unsigned short* __restrict__ rin) {
  int idx = blockIdx.x * 256 + threadIdx.x;
  int e = idx * 4;
  float4 v = *(const float4*)&x[e];
  ushort4 u;
  u.x = f2bf(v.x); u.y = f2bf(v.y); u.z = f2bf(v.z); u.w = f2bf(v.w);
  int row = e >> 9, col = e & 511;
  *(ushort4*)&rin[(size_t)row * 1024 + col] = u;
}

__global__ __launch_bounds__(256)
void transpose_kernel(const float* __restrict__ x, unsigned short* __restrict__ xT) {
  __shared__ unsigned short tile[64][65];
  const int b = blockIdx.z;
  const int j0 = blockIdx.x << 6, d0 = blockIdx.y << 6;
  const int tx = threadIdx.x & 63, ty = threadIdx.x >> 6;
  const float* xb = x + (size_t)b * 2048 * 512;
  unsigned short* xTb = xT + (size_t)b * 512 * 2048;
#pragma unroll
  for (int rep = 0; rep < 16; ++rep) {
    int jj = (rep << 2) + ty;
    tile[jj][tx] = f2bf(xb[(size_t)(j0 + jj) * 512 + d0 + tx]);
  }
  __syncthreads();
#pragma unroll
  for (int rep = 0; rep < 16; ++rep) {
    int dd = (rep << 2) + ty;
    xTb[(size_t)(d0 + dd) * 2048 + j0 + tx] = tile[tx][dd];
  }
}

__global__ __launch_bounds__(256)
void softmax_kernel(float* __restrict__ sbase) {
  __shared__ float red[8];
  const int i = blockIdx.x;
  float* sp = sbase + (size_t)i * 2048;
  const int tid = threadIdx.x;
  const int j0 = tid << 3;
  float4 va = *(const float4*)&sp[j0];
  float4 vb = *(const float4*)&sp[j0 + 4];
  float v[8] = {va.x, va.y, va.z, va.w, vb.x, vb.y, vb.z, vb.w};
#pragma unroll
  for (int k = 0; k < 8; ++k)
    if (j0 + k == i) v[k] = -1e30f;
  float m = v[0];
#pragma unroll
  for (int k = 1; k < 8; ++k) m = fmaxf(m, v[k]);
#pragma unroll
  for (int off = 32; off > 0; off >>= 1) m = fmaxf(m, __shfl_down(m, off, 64));
  if ((tid & 63) == 0) red[tid >> 6] = m;
  __syncthreads();
  m = fmaxf(fmaxf(red[0], red[1]), fmaxf(red[2], red[3]));
  float s = 0.f;
#pragma unroll
  for (int k = 0; k < 8; ++k) {
    float e = __expf(v[k] - m);
    if (j0 + k == i) e = 0.f;
    v[k] = e;
    s += e;
  }
#pragma unroll
  for (int off = 32; off > 0; off >>= 1) s += __shfl_down(s, off, 64);
  if ((tid & 63) == 0) red[4 + (tid >> 6)] = s;
  __syncthreads();
  s = red[4] + red[5] + red[6] + red[7];
  float inv = 1.f / s;
  unsigned int pk[4];
#pragma unroll
  for (int k = 0; k < 4; ++k) {
    unsigned int lo = f2bf(v[2 * k] * inv);
    unsigned int hi = f2bf(v[2 * k + 1] * inv);
    pk[k] = lo | (hi << 16);
  }
  uint4 o; o.x = pk[0]; o.y = pk[1]; o.z = pk[2]; o.w = pk[3];
  *(uint4*)&((unsigned short*)sp)[j0] = o;
}

// ---------------- persistent bidirectional GRU ------------------------------
// 64 WGs: dir = wg>>5, slice = wg&31 owns 16 hidden units. Whh rows for those
// units live in registers as MFMA B-fragments.
// Exchange: each h element published as ONE atomic uint32 (h_bf16<<16 | tag),
// agent scope (MALL-coherent, proven transport). The 4B store can't tear, so
// the consumer's poll IS the data load: retry until all tags == t. No flags,
// no producer store-drain, no separate h load -> ~2 fewer MALL RTs per step.
// Double-buffered phases give distance-2 slack (tag reuse race-free).
__global__ __launch_bounds__(256)
void gru_kernel(const unsigned short* __restrict__ xw_f,
                const unsigned short* __restrict__ xw_b,
                const unsigned short* __restrict__ Whh_f,
                const unsigned short* __restrict__ Whh_b,
                const float* __restrict__ bhh_f,
                const float* __restrict__ bhh_b,
                unsigned short* __restrict__ hcat,
                unsigned int* __restrict__ hstate) { // [2 dir][2 phase][4096]
  const int wg = blockIdx.x;
  const int dir = wg >> 5;
  const int slice = wg & 31;
  const int u0 = slice << 4;
  const unsigned short* __restrict__ xwp = dir ? xw_b : xw_f;
  const unsigned short* __restrict__ Whh = dir ? Whh_b : Whh_f;
  const float* __restrict__ bhh = dir ? bhh_b : bhh_f;
  unsigned int* hstD = hstate + dir * 2 * 4096;

  __shared__ __attribute__((aligned(16))) unsigned short hbf[16 * 552];
  __shared__ float ghbuf[3 * 128];

  const int tid = threadIdx.x;
  const int w = tid >> 6, l = tid & 63;
  const int fr = l & 15, fk = (l >> 4) << 3;

  for (int i = tid; i < 16 * 552; i += 256) hbf[i] = 0;

  bfx8 wfrag[16];
  if (w < 3) {
    const int grow = (w << 9) + u0 + fr;  // gate*512 + unit
#pragma unroll
    for (int ks = 0; ks < 16; ++ks)
      wfrag[ks] = *(const bfx8*)&Whh[(size_t)grow * 512 + (ks << 5) + fk];
  }
  const int b_ = tid >> 4, uu_ = tid & 15;
  float bh0 = 0.f, bh1 = 0.f, bh2 = 0.f;
  if (tid < 128) {
    bh0 = bhh[u0 + uu_];
    bh1 = bhh[512 + u0 + uu_];
    bh2 = bhh[1024 + u0 + uu_];
  }
  __syncthreads();  // hbf zeroed (h_0 = 0), biases ready

  float xr = 0.f, xz = 0.f, xn = 0.f;
  if (tid < 128) {
    int ta = dir ? 2047 : 0;
    size_t rb = (size_t)(b_ * 2048 + ta) * 1536;
    xr = bf2f(xwp[rb + u0 + uu_]);
    xz = bf2f(xwp[rb + 512 + u0 + uu_]);
    xn = bf2f(xwp[rb + 1024 + u0 + uu_]);
  }

  // consumer-side constants: this thread owns elements [tid*16, tid*16+16)
  const int cb = tid >> 5;              // batch row 0..7
  const int cu = (tid & 31) << 4;       // unit offset 0..496
  unsigned int* const dstl = (unsigned int*)&hbf[cb * 552 + cu];

  for (int t = 0; t < 2048; ++t) {
    const int t_act = dir ? (2047 - t) : t;
    // ---- retry-load tagged h_t (all 256 threads; poll IS the data load) ----
    if (t > 0) {
      const unsigned int* hr = hstD + (t & 1) * 4096 + (tid << 4);
      const unsigned int tg = (unsigned int)t;
      unsigned int v0, v1, v2, v3, v4, v5, v6, v7;
      unsigned int v8, v9, va, vb, vc, vd, ve, vf;
      bool ok;
      do {
        v0 = __hip_atomic_load(hr + 0,  __ATOMIC_RELAXED, __HIP_MEMORY_SCOPE_AGENT);
        v1 = __hip_atomic_load(hr + 1,  __ATOMIC_RELAXED, __HIP_MEMORY_SCOPE_AGENT);
        v2 = __hip_atomic_load(hr + 2,  __ATOMIC_RELAXED, __HIP_MEMORY_SCOPE_AGENT);
        v3 = __hip_atomic_load(hr + 3,  __ATOMIC_RELAXED, __HIP_MEMORY_SCOPE_AGENT);
        v4 = __hip_atomic_load(hr + 4,  __ATOMIC_RELAXED, __HIP_MEMORY_SCOPE_AGENT);
        v5 = __hip_atomic_load(hr + 5,  __ATOMIC_RELAXED, __HIP_MEMORY_SCOPE_AGENT);
        v6 = __hip_atomic_load(hr + 6,  __ATOMIC_RELAXED, __HIP_MEMORY_SCOPE_AGENT);
        v7 = __hip_atomic_load(hr + 7,  __ATOMIC_RELAXED, __HIP_MEMORY_SCOPE_AGENT);
        v8 = __hip_atomic_load(hr + 8,  __ATOMIC_RELAXED, __HIP_MEMORY_SCOPE_AGENT);
        v9 = __hip_atomic_load(hr + 9,  __ATOMIC_RELAXED, __HIP_MEMORY_SCOPE_AGENT);
        va = __hip_atomic_load(hr + 10, __ATOMIC_RELAXED, __HIP_MEMORY_SCOPE_AGENT);
        vb = __hip_atomic_load(hr + 11, __ATOMIC_RELAXED, __HIP_MEMORY_SCOPE_AGENT);
        vc = __hip_atomic_load(hr + 12, __ATOMIC_RELAXED, __HIP_MEMORY_SCOPE_AGENT);
        vd = __hip_atomic_load(hr + 13, __ATOMIC_RELAXED, __HIP_MEMORY_SCOPE_AGENT);
        ve = __hip_atomic_load(hr + 14, __ATOMIC_RELAXED, __HIP_MEMORY_SCOPE_AGENT);
        vf = __hip_atomic_load(hr + 15, __ATOMIC_RELAXED, __HIP_MEMORY_SCOPE_AGENT);
        unsigned int and0 = v0 & v1 & v2 & v3 & v4 & v5 & v6 & v7;
        unsigned int and1 = v8 & v9 & va & vb & vc & vd & ve & vf;
        unsigned int or0 = v0 | v1 | v2 | v3 | v4 | v5 | v6 | v7;
        unsigned int or1 = v8 | v9 | va | vb | vc | vd | ve | vf;
        // all 16 low halves equal tg  <=>  AND of lows == tg == OR of lows
        ok = (((and0 & and1) & 0xffffu) == tg) && (((or0 | or1) & 0xffffu) == tg);
      } while (!ok);
      // unpack to LDS: dword q holds elements (2q, 2q+1) as bf16 pair
      dstl[0] = (v0 >> 16) | (v1 & 0xffff0000u);
      dstl[1] = (v2 >> 16) | (v3 & 0xffff0000u);
      dstl[2] = (v4 >> 16) | (v5 & 0xffff0000u);
      dstl[3] = (v6 >> 16) | (v7 & 0xffff0000u);
      dstl[4] = (v8 >> 16) | (v9 & 0xffff0000u);
      dstl[5] = (va >> 16) | (vb & 0xffff0000u);
      dstl[6] = (vc >> 16) | (vd & 0xffff0000u);
      dstl[7] = (ve >> 16) | (vf & 0xffff0000u);
    }
    __syncthreads();  // B1: h_t in LDS
    float hprev = 0.f;
    if (tid < 128) hprev = bf2f(hbf[b_ * 552 + u0 + uu_]);  // read before B2
    if (w < 3) {
      fx4 z4 = {0.f, 0.f, 0.f, 0.f};
      fx4 acc0 = z4, acc1 = z4;
#pragma unroll
      for (int ks = 0; ks < 16; ks += 2) {
        bfx8 a0 = *(const bfx8*)&hbf[fr * 552 + (ks << 5) + fk];
        bfx8 a1 = *(const bfx8*)&hbf[fr * 552 + ((ks + 1) << 5) + fk];
        acc0 = __builtin_amdgcn_mfma_f32_16x16x32_bf16(a0, wfrag[ks], acc0, 0, 0, 0);
        acc1 = __builtin_amdgcn_mfma_f32_16x16x32_bf16(a1, wfrag[ks + 1], acc1, 0, 0, 0);
      }
      if (l < 32) {
#pragma unroll
        for (int i = 0; i < 4; ++i) {
          int bb = ((l >> 4) << 2) + i;  // batch row 0..7
          ghbuf[(w << 7) + (bb << 4) + fr] = acc0[i] + acc1[i];
        }
      }
    }
    __syncthreads();  // B2: ghbuf ready; hbf now dead (refill allowed)
    if (tid < 128) {
      float ghr = ghbuf[tid] + bh0;
      float ghz = ghbuf[128 + tid] + bh1;
      float ghn = ghbuf[256 + tid] + bh2;
      float r = 1.f / (1.f + __expf(-(xr + ghr)));
      float z = 1.f / (1.f + __expf(-(xz + ghz)));
      float n = tanhf(xn + r * ghn);
      float hn = (1.f - z) * n + z * hprev;
      unsigned short hnb = f2bf(hn);
      // publish tagged h_{t+1} FIRST (critical path), then hcat, then prefetch
      unsigned int pv = ((unsigned int)hnb << 16) | (unsigned int)(t + 1);
      __hip_atomic_store(&hstD[((t + 1) & 1) * 4096 + (b_ << 9) + u0 + uu_], pv,
                         __ATOMIC_RELAXED, __HIP_MEMORY_SCOPE_AGENT);
      hcat[((size_t)(b_ * 2048 + t_act) << 10) + (dir << 9) + u0 + uu_] = hnb;
      if (t + 1 < 2048) {
        int ta = dir ? (2046 - t) : (t + 1);
        size_t rb = (size_t)(b_ * 2048 + ta) * 1536;
        xr = bf2f(xwp[rb + u0 + uu_]);
        xz = bf2f(xwp[rb + 512 + u0 + uu_]);
        xn = bf2f(xwp[rb + 1024 + u0 + uu_]);
      }
    }
  }
}

// ---------------------------------------------------------------------------
extern "C" void kernel_launch(void* const* d_in, const int* in_sizes, int n_in,
                              void* d_out, int out_size, void* d_ws, size_t ws_size,
                              hipStream_t stream) {
  (void)in_sizes; (void)n_in; (void)out_size;
  const float* x    = (const float*)d_in[0];
  const float* W    = (const float*)d_in[1];
  const float* Wg   = (const float*)d_in[2];
  const float* Wihf = (const float*)d_in[3];
  const float* Whhf = (const float*)d_in[4];
  const float* bihf = (const float*)d_in[5];
  const float* bhhf = (const float*)d_in[6];
  const float* Wihb = (const float*)d_in[7];
  const float* Whhb = (const float*)d_in[8];
  const float* bihb = (const float*)d_in[9];
  const float* bhhb = (const float*)d_in[10];
  const float* Wp   = (const float*)d_in[11];
  const float* bp   = (const float*)d_in[12];
  float* out = (float*)d_out;

  char* base = (char*)d_ws;
  size_t off = 0;
  auto alloc = [&](size_t b) { void* r = base + off; off += (b + 255) & ~(size_t)255; return r; };
  unsigned short* xT   = (unsigned short*)alloc(8ull * 512 * 2048 * 2);
  unsigned short* xwf  = (unsigned short*)alloc(16384ull * 1536 * 2);
  unsigned short* xwb  = (unsigned short*)alloc(16384ull * 1536 * 2);
  unsigned short* rin  = (unsigned short*)alloc(16384ull * 1024 * 2);
  unsigned short* ring = (unsigned short*)alloc(16384ull * 1024 * 2);
  unsigned short* wW   = (unsigned short*)alloc(512ull * 512 * 2);
  unsigned short* wWg  = (unsigned short*)alloc(1024ull * 1024 * 2);
  unsigned short* wIf  = (unsigned short*)alloc(1536ull * 1024 * 2);
  unsigned short* wHf  = (unsigned short*)alloc(1536ull * 512 * 2);
  unsigned short* wIb  = (unsigned short*)alloc(1536ull * 1024 * 2);
  unsigned short* wHb  = (unsigned short*)alloc(1536ull * 512 * 2);
  unsigned short* wP   = (unsigned short*)alloc(512ull * 1024 * 2);
  unsigned int*   hst  = (unsigned int*)alloc(2ull * 2 * 4096 * 4);
  // overlays (lifetimes disjoint):
  float* sbuf = (float*)xwf;           // s scores, dead before xw_f written
  unsigned short* wxbf = ring;         // Wx, dead before ring written
  unsigned short* hcat = rin;          // GRU output, written after rin dead
  if (off > ws_size) return;           // fail loudly (output stays poisoned)

  (void)hipMemsetAsync(hst, 0, 2 * 2 * 4096 * 4, stream);

  // weight casts
  cast_w_kernel<<<256,  256, 0, stream>>>(W,    wW,  512 * 512);
  cast_w_kernel<<<1024, 256, 0, stream>>>(Wg,   wWg, 1024 * 1024);
  cast_w_kernel<<<1536, 256, 0, stream>>>(Wihf, wIf, 1536 * 1024);
  cast_w_kernel<<<768,  256, 0, stream>>>(Whhf, wHf, 1536 * 512);
  cast_w_kernel<<<1536, 256, 0, stream>>>(Wihb, wIb, 1536 * 1024);
  cast_w_kernel<<<768,  256, 0, stream>>>(Whhb, wHb, 1536 * 512);
  cast_w_kernel<<<512,  256, 0, stream>>>(Wp,   wP,  512 * 1024);

  cast_x_kernel<<<8192, 256, 0, stream>>>(x, rin);
  transpose_kernel<<<dim3(32, 8, 8), 256, 0, stream>>>(x, xT);

  // Wx = x @ W^T  (A = rin left half)
  gemm_bt<EP_BF16><<<dim3(4, 128), 256, 0, stream>>>(rin, 1024, wW, 512, wxbf, 512, 512, nullptr, nullptr);

  // attention per batch: s -> softmax -> c (into rin[:,512:])
  for (int b = 0; b < 8; ++b) {
    gemm_bt<EP_F32><<<dim3(16, 16), 256, 0, stream>>>(
        wxbf + (size_t)b * 2048 * 512, 512, rin + (size_t)b * 2048 * 1024, 1024,
        sbuf, 2048, 512, nullptr, nullptr);
    softmax_kernel<<<2048, 256, 0, stream>>>(sbuf);
    gemm_bt<EP_BF16><<<dim3(4, 16), 256, 0, stream>>>(
        (const unsigned short*)sbuf, 4096, xT + (size_t)b * 512 * 2048, 2048,
        rin + (size_t)b * 2048 * 1024 + 512, 1024, 2048, nullptr, nullptr);
  }

  // gated concat: ring = rin * sigmoid(rin @ Wg^T)
  gemm_bt<EP_GATE><<<dim3(8, 128), 256, 0, stream>>>(rin, 1024, wWg, 1024, ring, 1024, 1024, rin, nullptr);

  // GRU input gates
  gemm_bt<EP_BIASBF><<<dim3(12, 128), 256, 0, stream>>>(ring, 1024, wIf, 1024, xwf, 1536, 1024, nullptr, bihf);
  gemm_bt<EP_BIASBF><<<dim3(12, 128), 256, 0, stream>>>(ring, 1024, wIb, 1024, xwb, 1536, 1024, nullptr, bihb);

  // persistent bidirectional GRU scan (writes hcat over rin region)
  gru_kernel<<<64, 256, 0, stream>>>(xwf, xwb, wHf, wHb, bhhf, bhhb, hcat, hst);

  // out = x + hcat @ Wp^T + bp
  gemm_bt<EP_RESID><<<dim3(4, 128), 256, 0, stream>>>(hcat, 1024, wP, 1024, out, 512, 1024, x, bp);
}

// Round 6
// 9663.113 us; speedup vs baseline: 1.0954x; 1.0954x over previous
//
#include <hip/hip_runtime.h>
#include <stdint.h>
#include <math.h>

// ---------------------------------------------------------------------------
// GatedMultiplicativeSelfAttention: B=8, S=2048, D=512, H=512
// GRU scan: 16 WGs (8 per direction), 64 units/WG, R2-style flag+ack protocol
// (proven transport), per-thread poll->load fusion, gates fused in MFMA waves.
// ---------------------------------------------------------------------------

typedef __attribute__((ext_vector_type(8))) short bfx8;
typedef __attribute__((ext_vector_type(4))) float fx4;

__device__ __forceinline__ float bf2f(unsigned short u) {
  union { unsigned int i; float f; } v; v.i = ((unsigned int)u) << 16; return v.f;
}
__device__ __forceinline__ unsigned short f2bf(float f) {
  union { float f; unsigned int i; } v; v.f = f;
  unsigned int x = v.i;
  return (unsigned short)((x + 0x7fffu + ((x >> 16) & 1u)) >> 16);
}

// ---------------- generic BT GEMM: C[M,N] = A[M,K] * B[N,K]^T ---------------
#define EP_BF16 0
#define EP_F32 1
#define EP_GATE 2
#define EP_RESID 3
#define EP_BIASBF 4

template <int EP>
__global__ __launch_bounds__(256)
void gemm_bt(const unsigned short* __restrict__ A, int lda,
             const unsigned short* __restrict__ B, int ldb,
             void* __restrict__ Cp, int ldc, int K,
             const void* __restrict__ P, const float* __restrict__ bias) {
  __shared__ __attribute__((aligned(16))) unsigned short As[128 * 64];
  __shared__ __attribute__((aligned(16))) unsigned short Bs[128 * 64];
  const int tid = threadIdx.x;
  const int w = tid >> 6, l = tid & 63;
  const int bm = blockIdx.y << 7, bn = blockIdx.x << 7;
  const int wm = (w >> 1) << 6, wn = (w & 1) << 6;
  const int fr = l & 15, fk = (l >> 4) << 3;
  fx4 zero4 = {0.f, 0.f, 0.f, 0.f};
  fx4 acc[4][4];
#pragma unroll
  for (int i = 0; i < 4; ++i)
#pragma unroll
    for (int j = 0; j < 4; ++j) acc[i][j] = zero4;

  for (int k0 = 0; k0 < K; k0 += 64) {
#pragma unroll
    for (int c = 0; c < 4; ++c) {
      int e = (tid + (c << 8)) << 3;
      int r = e >> 6, cc = e & 63;
      *(uint4*)&As[e] = *(const uint4*)&A[(size_t)(bm + r) * lda + k0 + cc];
      *(uint4*)&Bs[e] = *(const uint4*)&B[(size_t)(bn + r) * ldb + k0 + cc];
    }
    __syncthreads();
#pragma unroll
    for (int kk = 0; kk < 64; kk += 32) {
      bfx8 a[4], b[4];
#pragma unroll
      for (int m = 0; m < 4; ++m) a[m] = *(const bfx8*)&As[(wm + (m << 4) + fr) * 64 + kk + fk];
#pragma unroll
      for (int n = 0; n < 4; ++n) b[n] = *(const bfx8*)&Bs[(wn + (n << 4) + fr) * 64 + kk + fk];
#pragma unroll
      for (int m = 0; m < 4; ++m)
#pragma unroll
        for (int n = 0; n < 4; ++n)
          acc[m][n] = __builtin_amdgcn_mfma_f32_16x16x32_bf16(a[m], b[n], acc[m][n], 0, 0, 0);
    }
    __syncthreads();
  }
  const int er = (l >> 4) << 2, ec = l & 15;
#pragma unroll
  for (int m = 0; m < 4; ++m)
#pragma unroll
    for (int n = 0; n < 4; ++n)
#pragma unroll
      for (int i = 0; i < 4; ++i) {
        int gr = bm + wm + (m << 4) + er + i;
        int gc = bn + wn + (n << 4) + ec;
        float v = acc[m][n][i];
        size_t idx = (size_t)gr * ldc + gc;
        if constexpr (EP == EP_F32) {
          ((float*)Cp)[idx] = v;
        } else if constexpr (EP == EP_BF16) {
          ((unsigned short*)Cp)[idx] = f2bf(v);
        } else if constexpr (EP == EP_BIASBF) {
          ((unsigned short*)Cp)[idx] = f2bf(v + bias[gc]);
        } else if constexpr (EP == EP_GATE) {
          float rv = bf2f(((const unsigned short*)P)[idx]);
          float sg = 1.f / (1.f + __expf(-v));
          ((unsigned short*)Cp)[idx] = f2bf(rv * sg);
        } else {  // EP_RESID
          float xv = ((const float*)P)[idx];
          ((float*)Cp)[idx] = v + xv + bias[gc];
        }
      }
}

// ---------------- small prep kernels ----------------------------------------
__global__ __launch_bounds__(256)
void cast_w_kernel(const float* __restrict__ in, unsigned short* __restrict__ out, int n) {
  int e = (blockIdx.x * 256 + threadIdx.x) * 4;
  if (e >= n) return;
  float4 v = *(const float4*)&in[e];
  ushort4 u;
  u.x = f2bf(v.x); u.y = f2bf(v.y); u.z = f2bf(v.z); u.w = f2bf(v.w);
  *(ushort4*)&out[e] = u;
}

__global__ __launch_bounds__(256)
void cast_x_kernel(const float* __restrict__ x, unsigned short* __restrict__ rin) {
  int idx = blockIdx.x * 256 + threadIdx.x;
  int e = idx * 4;
  float4 v = *(const float4*)&x[e];
  ushort4 u;
  u.x = f2bf(v.x); u.y = f2bf(v.y); u.z = f2bf(v.z); u.w = f2bf(v.w);
  int row = e >> 9, col = e & 511;
  *(ushort4*)&rin[(size_t)row * 1024 + col] = u;
}

__global__ __launch_bounds__(256)
void transpose_kernel(const float* __restrict__ x, unsigned short* __restrict__ xT) {
  __shared__ unsigned short tile[64][65];
  const int b = blockIdx.z;
  const int j0 = blockIdx.x << 6, d0 = blockIdx.y << 6;
  const int tx = threadIdx.x & 63, ty = threadIdx.x >> 6;
  const float* xb = x + (size_t)b * 2048 * 512;
  unsigned short* xTb = xT + (size_t)b * 512 * 2048;
#pragma unroll
  for (int rep = 0; rep < 16; ++rep) {
    int jj = (rep << 2) + ty;
    tile[jj][tx] = f2bf(xb[(size_t)(j0 + jj) * 512 + d0 + tx]);
  }
  __syncthreads();
#pragma unroll
  for (int rep = 0; rep < 16; ++rep) {
    int dd = (rep << 2) + ty;
    xTb[(size_t)(d0 + dd) * 2048 + j0 + tx] = tile[tx][dd];
  }
}

__global__ __launch_bounds__(256)
void softmax_kernel(float* __restrict__ sbase) {
  __shared__ float red[8];
  const int i = blockIdx.x;
  float* sp = sbase + (size_t)i * 2048;
  const int tid = threadIdx.x;
  const int j0 = tid << 3;
  float4 va = *(const float4*)&sp[j0];
  float4 vb = *(const float4*)&sp[j0 + 4];
  float v[8] = {va.x, va.y, va.z, va.w, vb.x, vb.y, vb.z, vb.w};
#pragma unroll
  for (int k = 0; k < 8; ++k)
    if (j0 + k == i) v[k] = -1e30f;
  float m = v[0];
#pragma unroll
  for (int k = 1; k < 8; ++k) m = fmaxf(m, v[k]);
#pragma unroll
  for (int off = 32; off > 0; off >>= 1) m = fmaxf(m, __shfl_down(m, off, 64));
  if ((tid & 63) == 0) red[tid >> 6] = m;
  __syncthreads();
  m = fmaxf(fmaxf(red[0], red[1]), fmaxf(red[2], red[3]));
  float s = 0.f;
#pragma unroll
  for (int k = 0; k < 8; ++k) {
    float e = __expf(v[k] - m);
    if (j0 + k == i) e = 0.f;
    v[k] = e;
    s += e;
  }
#pragma unroll
  for (int off = 32; off > 0; off >>= 1) s += __shfl_down(s, off, 64);
  if ((tid & 63) == 0) red[4 + (tid >> 6)] = s;
  __syncthreads();
  s = red[4] + red[5] + red[6] + red[7];
  float inv = 1.f / s;
  unsigned int pk[4];
#pragma unroll
  for (int k = 0; k < 4; ++k) {
    unsigned int lo = f2bf(v[2 * k] * inv);
    unsigned int hi = f2bf(v[2 * k + 1] * inv);
    pk[k] = lo | (hi << 16);
  }
  uint4 o; o.x = pk[0]; o.y = pk[1]; o.z = pk[2]; o.w = pk[3];
  *(uint4*)&((unsigned short*)sp)[j0] = o;
}

// ---------------- persistent bidirectional GRU ------------------------------
// 16 WGs: dir = wg>>3, slice = wg&7 owns 64 units. Wave w owns 16 units
// (all 3 gates -> gates fused in-register, no ghbuf/B2). 192 weight VGPRs.
// Protocol (R2-proven): publish h (packed dwords, agent atomics) -> vmcnt(0)
// ack -> barrier -> per-WG flag. Consumer threads each poll ONLY the flag of
// the producer whose 32B region they load (poll->load fused, no barrier
// between). xw staged to LDS by lanes 32-63 during the previous step's tail.
__global__ __launch_bounds__(256, 1)
void gru_kernel(const unsigned short* __restrict__ xw_f,
                const unsigned short* __restrict__ xw_b,
                const unsigned short* __restrict__ Whh_f,
                const unsigned short* __restrict__ Whh_b,
                const float* __restrict__ bhh_f,
                const float* __restrict__ bhh_b,
                unsigned short* __restrict__ hcat,
                unsigned int* __restrict__ hstate,  // [2 dir][2 phase][2048 dw]
                unsigned int* __restrict__ flags) { // [2 dir][8 wg][32 pad]
  const int wg = blockIdx.x;
  const int dir = wg >> 3;
  const int slice = wg & 7;
  const unsigned short* __restrict__ xwp = dir ? xw_b : xw_f;
  const unsigned short* __restrict__ Whh = dir ? Whh_b : Whh_f;
  const float* __restrict__ bhh = dir ? bhh_b : bhh_f;
  unsigned int* hstD = hstate + dir * 2 * 2048;
  unsigned int* myflags = flags + dir * 8 * 32;

  __shared__ __attribute__((aligned(16))) unsigned short hbf[16 * 552];
  __shared__ unsigned int xwb_lds[4 * 3 * 8 * 8];  // [wave][gate][batch][dq]

  const int tid = threadIdx.x;
  const int w = tid >> 6, l = tid & 63;
  const int fr = l & 15, fk = (l >> 4) << 3;
  const int gu0 = slice * 64 + w * 16;   // wave's global unit base
  const int ul = l & 15;                 // unit-in-wave (lanes<32 gate work)
  const int ug = gu0 + ul;               // global unit for this lane

  for (int i = tid; i < 16 * 552; i += 256) hbf[i] = 0;

  // Whh B-fragments: 3 gates x 16 k-slices, register-resident (192 VGPRs)
  bfx8 wfrag[3][16];
#pragma unroll
  for (int g = 0; g < 3; ++g) {
    const size_t rowb = (size_t)(g * 512 + gu0 + fr) * 512;
#pragma unroll
    for (int ks = 0; ks < 16; ++ks)
      wfrag[g][ks] = *(const bfx8*)&Whh[rowb + (ks << 5) + fk];
  }
  float bh0 = 0.f, bh1 = 0.f, bh2 = 0.f;
  if (l < 32) {
    bh0 = bhh[ug];
    bh1 = bhh[512 + ug];
    bh2 = bhh[1024 + ug];
  }
  // stage xw for t=0 (upper lanes)
  if (l >= 32) {
    const int j = l - 32;
    const int ta0 = dir ? 2047 : 0;
#pragma unroll
    for (int q = 0; q < 6; ++q) {
      int e = j * 6 + q;
      int g = e >> 6, b = (e >> 3) & 7, dq = e & 7;
      unsigned int v = *(const unsigned int*)
          &xwp[(size_t)(b * 2048 + ta0) * 1536 + g * 512 + gu0 + dq * 2];
      xwb_lds[((w * 3 + g) * 8 + b) * 8 + dq] = v;
    }
  }
  // consumer mapping: thread loads dwords [tid*8, tid*8+8) of packed h
  const int cb = tid >> 5;                       // batch row
  const int cu = (tid & 31) << 4;                // first unit (16 units)
  const int cp = (tid & 31) >> 2;                // producer WG slice
  unsigned int* const dstl = (unsigned int*)&hbf[cb * 552 + cu];
  const unsigned int* const fp = &myflags[cp << 5];
  __syncthreads();

  for (int t = 0; t < 2048; ++t) {
    const int t_act = dir ? (2047 - t) : t;
    // ---- poll own producer's flag, then load region (no barrier between) --
    if (t > 0) {
      while (__hip_atomic_load(fp, __ATOMIC_RELAXED, __HIP_MEMORY_SCOPE_AGENT)
             < (unsigned int)t) {}
      const unsigned int* hr = hstD + (t & 1) * 2048 + (tid << 3);
      unsigned int v0 = __hip_atomic_load(hr + 0, __ATOMIC_RELAXED, __HIP_MEMORY_SCOPE_AGENT);
      unsigned int v1 = __hip_atomic_load(hr + 1, __ATOMIC_RELAXED, __HIP_MEMORY_SCOPE_AGENT);
      unsigned int v2 = __hip_atomic_load(hr + 2, __ATOMIC_RELAXED, __HIP_MEMORY_SCOPE_AGENT);
      unsigned int v3 = __hip_atomic_load(hr + 3, __ATOMIC_RELAXED, __HIP_MEMORY_SCOPE_AGENT);
      unsigned int v4 = __hip_atomic_load(hr + 4, __ATOMIC_RELAXED, __HIP_MEMORY_SCOPE_AGENT);
      unsigned int v5 = __hip_atomic_load(hr + 5, __ATOMIC_RELAXED, __HIP_MEMORY_SCOPE_AGENT);
      unsigned int v6 = __hip_atomic_load(hr + 6, __ATOMIC_RELAXED, __HIP_MEMORY_SCOPE_AGENT);
      unsigned int v7 = __hip_atomic_load(hr + 7, __ATOMIC_RELAXED, __HIP_MEMORY_SCOPE_AGENT);
      dstl[0] = v0; dstl[1] = v1; dstl[2] = v2; dstl[3] = v3;
      dstl[4] = v4; dstl[5] = v5; dstl[6] = v6; dstl[7] = v7;
    }
    __syncthreads();  // B1: h_t in LDS
    // ---- MFMA: gh for this wave's 16 units x 3 gates -----------------------
    fx4 z4 = {0.f, 0.f, 0.f, 0.f};
    fx4 acc0 = z4, acc1 = z4, acc2 = z4;
#pragma unroll
    for (int ks = 0; ks < 16; ++ks) {
      bfx8 a = *(const bfx8*)&hbf[fr * 552 + (ks << 5) + fk];
      acc0 = __builtin_amdgcn_mfma_f32_16x16x32_bf16(a, wfrag[0][ks], acc0, 0, 0, 0);
      acc1 = __builtin_amdgcn_mfma_f32_16x16x32_bf16(a, wfrag[1][ks], acc1, 0, 0, 0);
      acc2 = __builtin_amdgcn_mfma_f32_16x16x32_bf16(a, wfrag[2][ks], acc2, 0, 0, 0);
    }
    // ---- gates fused in-register (lanes<32; batch=(l>>4)*4+i, unit=ug) ----
    unsigned short hnb[4];
    unsigned int pack[4];
#pragma unroll
    for (int i = 0; i < 4; ++i) {
      const int b = ((l >> 4) << 2) + i;
      float xr = 0.f, xz = 0.f, xn = 0.f, hprev = 0.f;
      if (l < 32) {
        unsigned int dr = xwb_lds[((w * 3 + 0) * 8 + b) * 8 + (ul >> 1)];
        unsigned int dz = xwb_lds[((w * 3 + 1) * 8 + b) * 8 + (ul >> 1)];
        unsigned int dn = xwb_lds[((w * 3 + 2) * 8 + b) * 8 + (ul >> 1)];
        const int sh = (ul & 1) << 4;
        xr = bf2f((unsigned short)(dr >> sh));
        xz = bf2f((unsigned short)(dz >> sh));
        xn = bf2f((unsigned short)(dn >> sh));
        hprev = bf2f(hbf[b * 552 + ug]);
      }
      float r = 1.f / (1.f + __expf(-(xr + acc0[i] + bh0)));
      float z = 1.f / (1.f + __expf(-(xz + acc1[i] + bh1)));
      float n = tanhf(xn + r * (acc2[i] + bh2));
      float hn = (1.f - z) * n + z * hprev;
      hnb[i] = f2bf(hn);
      unsigned int partner = (unsigned int)__shfl_down((int)hnb[i], 1);
      pack[i] = (unsigned int)hnb[i] | (partner << 16);
    }
    if (l < 32 && !(ul & 1)) {
      unsigned int* hw = hstD + ((t + 1) & 1) * 2048 + (ug >> 1);
#pragma unroll
      for (int i = 0; i < 4; ++i) {
        const int b = ((l >> 4) << 2) + i;
        __hip_atomic_store(hw + (b << 8), pack[i],
                           __ATOMIC_RELAXED, __HIP_MEMORY_SCOPE_AGENT);
      }
    }
    asm volatile("s_waitcnt vmcnt(0)" ::: "memory");  // ack publishes
    __syncthreads();  // B2: all publishes acked; hbf fully consumed
    if (tid == 0 && t + 1 < 2048)
      __hip_atomic_store(&myflags[slice << 5], (unsigned int)(t + 1),
                         __ATOMIC_RELAXED, __HIP_MEMORY_SCOPE_AGENT);
    // ---- off-critical-path tail: hcat stores + next xw stage --------------
    if (l < 32) {
#pragma unroll
      for (int i = 0; i < 4; ++i) {
        const int b = ((l >> 4) << 2) + i;
        hcat[((size_t)(b * 2048 + t_act) << 10) + (dir << 9) + ug] = hnb[i];
      }
    } else if (t + 1 < 2048) {
      const int j = l - 32;
      const int ta = dir ? (2046 - t) : (t + 1);
#pragma unroll
      for (int q = 0; q < 6; ++q) {
        int e = j * 6 + q;
        int g = e >> 6, b = (e >> 3) & 7, dq = e & 7;
        unsigned int v = *(const unsigned int*)
            &xwp[(size_t)(b * 2048 + ta) * 1536 + g * 512 + gu0 + dq * 2];
        xwb_lds[((w * 3 + g) * 8 + b) * 8 + dq] = v;
      }
    }
  }
}

// ---------------------------------------------------------------------------
extern "C" void kernel_launch(void* const* d_in, const int* in_sizes, int n_in,
                              void* d_out, int out_size, void* d_ws, size_t ws_size,
                              hipStream_t stream) {
  (void)in_sizes; (void)n_in; (void)out_size;
  const float* x    = (const float*)d_in[0];
  const float* W    = (const float*)d_in[1];
  const float* Wg   = (const float*)d_in[2];
  const float* Wihf = (const float*)d_in[3];
  const float* Whhf = (const float*)d_in[4];
  const float* bihf = (const float*)d_in[5];
  const float* bhhf = (const float*)d_in[6];
  const float* Wihb = (const float*)d_in[7];
  const float* Whhb = (const float*)d_in[8];
  const float* bihb = (const float*)d_in[9];
  const float* bhhb = (const float*)d_in[10];
  const float* Wp   = (const float*)d_in[11];
  const float* bp   = (const float*)d_in[12];
  float* out = (float*)d_out;

  char* base = (char*)d_ws;
  size_t off = 0;
  auto alloc = [&](size_t b) { void* r = base + off; off += (b + 255) & ~(size_t)255; return r; };
  unsigned short* xT   = (unsigned short*)alloc(8ull * 512 * 2048 * 2);
  unsigned short* xwf  = (unsigned short*)alloc(16384ull * 1536 * 2);
  unsigned short* xwb  = (unsigned short*)alloc(16384ull * 1536 * 2);
  unsigned short* rin  = (unsigned short*)alloc(16384ull * 1024 * 2);
  unsigned short* ring = (unsigned short*)alloc(16384ull * 1024 * 2);
  unsigned short* wW   = (unsigned short*)alloc(512ull * 512 * 2);
  unsigned short* wWg  = (unsigned short*)alloc(1024ull * 1024 * 2);
  unsigned short* wIf  = (unsigned short*)alloc(1536ull * 1024 * 2);
  unsigned short* wHf  = (unsigned short*)alloc(1536ull * 512 * 2);
  unsigned short* wIb  = (unsigned short*)alloc(1536ull * 1024 * 2);
  unsigned short* wHb  = (unsigned short*)alloc(1536ull * 512 * 2);
  unsigned short* wP   = (unsigned short*)alloc(512ull * 1024 * 2);
  unsigned int*   hst  = (unsigned int*)alloc(2ull * 2 * 2048 * 4);
  unsigned int*   flg  = (unsigned int*)alloc(2048);
  // overlays (lifetimes disjoint):
  float* sbuf = (float*)xwf;           // s scores, dead before xw_f written
  unsigned short* wxbf = ring;         // Wx, dead before ring written
  unsigned short* hcat = rin;          // GRU output, written after rin dead
  if (off > ws_size) return;           // fail loudly (output stays poisoned)

  (void)hipMemsetAsync(hst, 0, 2 * 2 * 2048 * 4, stream);
  (void)hipMemsetAsync(flg, 0, 2048, stream);

  // weight casts
  cast_w_kernel<<<256,  256, 0, stream>>>(W,    wW,  512 * 512);
  cast_w_kernel<<<1024, 256, 0, stream>>>(Wg,   wWg, 1024 * 1024);
  cast_w_kernel<<<1536, 256, 0, stream>>>(Wihf, wIf, 1536 * 1024);
  cast_w_kernel<<<768,  256, 0, stream>>>(Whhf, wHf, 1536 * 512);
  cast_w_kernel<<<1536, 256, 0, stream>>>(Wihb, wIb, 1536 * 1024);
  cast_w_kernel<<<768,  256, 0, stream>>>(Whhb, wHb, 1536 * 512);
  cast_w_kernel<<<512,  256, 0, stream>>>(Wp,   wP,  512 * 1024);

  cast_x_kernel<<<8192, 256, 0, stream>>>(x, rin);
  transpose_kernel<<<dim3(32, 8, 8), 256, 0, stream>>>(x, xT);

  // Wx = x @ W^T  (A = rin left half)
  gemm_bt<EP_BF16><<<dim3(4, 128), 256, 0, stream>>>(rin, 1024, wW, 512, wxbf, 512, 512, nullptr, nullptr);

  // attention per batch: s -> softmax -> c (into rin[:,512:])
  for (int b = 0; b < 8; ++b) {
    gemm_bt<EP_F32><<<dim3(16, 16), 256, 0, stream>>>(
        wxbf + (size_t)b * 2048 * 512, 512, rin + (size_t)b * 2048 * 1024, 1024,
        sbuf, 2048, 512, nullptr, nullptr);
    softmax_kernel<<<2048, 256, 0, stream>>>(sbuf);
    gemm_bt<EP_BF16><<<dim3(4, 16), 256, 0, stream>>>(
        (const unsigned short*)sbuf, 4096, xT + (size_t)b * 512 * 2048, 2048,
        rin + (size_t)b * 2048 * 1024 + 512, 1024, 2048, nullptr, nullptr);
  }

  // gated concat: ring = rin * sigmoid(rin @ Wg^T)
  gemm_bt<EP_GATE><<<dim3(8, 128), 256, 0, stream>>>(rin, 1024, wWg, 1024, ring, 1024, 1024, rin, nullptr);

  // GRU input gates
  gemm_bt<EP_BIASBF><<<dim3(12, 128), 256, 0, stream>>>(ring, 1024, wIf, 1024, xwf, 1536, 1024, nullptr, bihf);
  gemm_bt<EP_BIASBF><<<dim3(12, 128), 256, 0, stream>>>(ring, 1024, wIb, 1024, xwb, 1536, 1024, nullptr, bihb);

  // persistent bidirectional GRU scan (writes hcat over rin region)
  gru_kernel<<<16, 256, 0, stream>>>(xwf, xwb, wHf, wHb, bhhf, bhhb, hcat, hst, flg);

  // out = x + hcat @ Wp^T + bp
  gemm_bt<EP_RESID><<<dim3(4, 128), 256, 0, stream>>>(hcat, 1024, wP, 1024, out, 512, 1024, x, bp);
}

// Round 7
// 7193.527 us; speedup vs baseline: 1.4715x; 1.3433x over previous
//
#include <hip/hip_runtime.h>
#include <stdint.h>
#include <math.h>

// ---------------------------------------------------------------------------
// GatedMultiplicativeSelfAttention: B=8, S=2048, D=512, H=512
// GRU scan: 64 WGs (32/dir, 16 units each, R2 geometry -> 64 weight VGPRs,
// no spill). Protocol: per-wave region flags + per-thread poll->load fusion,
// 2 barriers/step. Transport = agent-scope atomics (MALL), proven R2/R6.
// ---------------------------------------------------------------------------

typedef __attribute__((ext_vector_type(8))) short bfx8;
typedef __attribute__((ext_vector_type(4))) float fx4;

__device__ __forceinline__ float bf2f(unsigned short u) {
  union { unsigned int i; float f; } v; v.i = ((unsigned int)u) << 16; return v.f;
}
__device__ __forceinline__ unsigned short f2bf(float f) {
  union { float f; unsigned int i; } v; v.f = f;
  unsigned int x = v.i;
  return (unsigned short)((x + 0x7fffu + ((x >> 16) & 1u)) >> 16);
}

// ---------------- generic BT GEMM: C[M,N] = A[M,K] * B[N,K]^T ---------------
#define EP_BF16 0
#define EP_F32 1
#define EP_GATE 2
#define EP_RESID 3
#define EP_BIASBF 4

template <int EP>
__global__ __launch_bounds__(256)
void gemm_bt(const unsigned short* __restrict__ A, int lda,
             const unsigned short* __restrict__ B, int ldb,
             void* __restrict__ Cp, int ldc, int K,
             const void* __restrict__ P, const float* __restrict__ bias) {
  __shared__ __attribute__((aligned(16))) unsigned short As[128 * 64];
  __shared__ __attribute__((aligned(16))) unsigned short Bs[128 * 64];
  const int tid = threadIdx.x;
  const int w = tid >> 6, l = tid & 63;
  const int bm = blockIdx.y << 7, bn = blockIdx.x << 7;
  const int wm = (w >> 1) << 6, wn = (w & 1) << 6;
  const int fr = l & 15, fk = (l >> 4) << 3;
  fx4 zero4 = {0.f, 0.f, 0.f, 0.f};
  fx4 acc[4][4];
#pragma unroll
  for (int i = 0; i < 4; ++i)
#pragma unroll
    for (int j = 0; j < 4; ++j) acc[i][j] = zero4;

  for (int k0 = 0; k0 < K; k0 += 64) {
#pragma unroll
    for (int c = 0; c < 4; ++c) {
      int e = (tid + (c << 8)) << 3;
      int r = e >> 6, cc = e & 63;
      *(uint4*)&As[e] = *(const uint4*)&A[(size_t)(bm + r) * lda + k0 + cc];
      *(uint4*)&Bs[e] = *(const uint4*)&B[(size_t)(bn + r) * ldb + k0 + cc];
    }
    __syncthreads();
#pragma unroll
    for (int kk = 0; kk < 64; kk += 32) {
      bfx8 a[4], b[4];
#pragma unroll
      for (int m = 0; m < 4; ++m) a[m] = *(const bfx8*)&As[(wm + (m << 4) + fr) * 64 + kk + fk];
#pragma unroll
      for (int n = 0; n < 4; ++n) b[n] = *(const bfx8*)&Bs[(wn + (n << 4) + fr) * 64 + kk + fk];
#pragma unroll
      for (int m = 0; m < 4; ++m)
#pragma unroll
        for (int n = 0; n < 4; ++n)
          acc[m][n] = __builtin_amdgcn_mfma_f32_16x16x32_bf16(a[m], b[n], acc[m][n], 0, 0, 0);
    }
    __syncthreads();
  }
  const int er = (l >> 4) << 2, ec = l & 15;
#pragma unroll
  for (int m = 0; m < 4; ++m)
#pragma unroll
    for (int n = 0; n < 4; ++n)
#pragma unroll
      for (int i = 0; i < 4; ++i) {
        int gr = bm + wm + (m << 4) + er + i;
        int gc = bn + wn + (n << 4) + ec;
        float v = acc[m][n][i];
        size_t idx = (size_t)gr * ldc + gc;
        if constexpr (EP == EP_F32) {
          ((float*)Cp)[idx] = v;
        } else if constexpr (EP == EP_BF16) {
          ((unsigned short*)Cp)[idx] = f2bf(v);
        } else if constexpr (EP == EP_BIASBF) {
          ((unsigned short*)Cp)[idx] = f2bf(v + bias[gc]);
        } else if constexpr (EP == EP_GATE) {
          float rv = bf2f(((const unsigned short*)P)[idx]);
          float sg = 1.f / (1.f + __expf(-v));
          ((unsigned short*)Cp)[idx] = f2bf(rv * sg);
        } else {  // EP_RESID
          float xv = ((const float*)P)[idx];
          ((float*)Cp)[idx] = v + xv + bias[gc];
        }
      }
}

// ---------------- small prep kernels ----------------------------------------
__global__ __launch_bounds__(256)
void cast_w_kernel(const float* __restrict__ in, unsigned short* __restrict__ out, int n) {
  int e = (blockIdx.x * 256 + threadIdx.x) * 4;
  if (e >= n) return;
  float4 v = *(const float4*)&in[e];
  ushort4 u;
  u.x = f2bf(v.x); u.y = f2bf(v.y); u.z = f2bf(v.z); u.w = f2bf(v.w);
  *(ushort4*)&out[e] = u;
}

__global__ __launch_bounds__(256)
void cast_x_kernel(const float* __restrict__ x, unsigned short* __restrict__ rin) {
  int idx = blockIdx.x * 256 + threadIdx.x;
  int e = idx * 4;
  float4 v = *(const float4*)&x[e];
  ushort4 u;
  u.x = f2bf(v.x); u.y = f2bf(v.y); u.z = f2bf(v.z); u.w = f2bf(v.w);
  int row = e >> 9, col = e & 511;
  *(ushort4*)&rin[(size_t)row * 1024 + col] = u;
}

__global__ __launch_bounds__(256)
void transpose_kernel(const float* __restrict__ x, unsigned short* __restrict__ xT) {
  __shared__ unsigned short tile[64][65];
  const int b = blockIdx.z;
  const int j0 = blockIdx.x << 6, d0 = blockIdx.y << 6;
  const int tx = threadIdx.x & 63, ty = threadIdx.x >> 6;
  const float* xb = x + (size_t)b * 2048 * 512;
  unsigned short* xTb = xT + (size_t)b * 512 * 2048;
#pragma unroll
  for (int rep = 0; rep < 16; ++rep) {
    int jj = (rep << 2) + ty;
    tile[jj][tx] = f2bf(xb[(size_t)(j0 + jj) * 512 + d0 + tx]);
  }
  __syncthreads();
#pragma unroll
  for (int rep = 0; rep < 16; ++rep) {
    int dd = (rep << 2) + ty;
    xTb[(size_t)(d0 + dd) * 2048 + j0 + tx] = tile[tx][dd];
  }
}

__global__ __launch_bounds__(256)
void softmax_kernel(float* __restrict__ sbase) {
  __shared__ float red[8];
  const int i = blockIdx.x;
  float* sp = sbase + (size_t)i * 2048;
  const int tid = threadIdx.x;
  const int j0 = tid << 3;
  float4 va = *(const float4*)&sp[j0];
  float4 vb = *(const float4*)&sp[j0 + 4];
  float v[8] = {va.x, va.y, va.z, va.w, vb.x, vb.y, vb.z, vb.w};
#pragma unroll
  for (int k = 0; k < 8; ++k)
    if (j0 + k == i) v[k] = -1e30f;
  float m = v[0];
#pragma unroll
  for (int k = 1; k < 8; ++k) m = fmaxf(m, v[k]);
#pragma unroll
  for (int off = 32; off > 0; off >>= 1) m = fmaxf(m, __shfl_down(m, off, 64));
  if ((tid & 63) == 0) red[tid >> 6] = m;
  __syncthreads();
  m = fmaxf(fmaxf(red[0], red[1]), fmaxf(red[2], red[3]));
  float s = 0.f;
#pragma unroll
  for (int k = 0; k < 8; ++k) {
    float e = __expf(v[k] - m);
    if (j0 + k == i) e = 0.f;
    v[k] = e;
    s += e;
  }
#pragma unroll
  for (int off = 32; off > 0; off >>= 1) s += __shfl_down(s, off, 64);
  if ((tid & 63) == 0) red[4 + (tid >> 6)] = s;
  __syncthreads();
  s = red[4] + red[5] + red[6] + red[7];
  float inv = 1.f / s;
  unsigned int pk[4];
#pragma unroll
  for (int k = 0; k < 4; ++k) {
    unsigned int lo = f2bf(v[2 * k] * inv);
    unsigned int hi = f2bf(v[2 * k + 1] * inv);
    pk[k] = lo | (hi << 16);
  }
  uint4 o; o.x = pk[0]; o.y = pk[1]; o.z = pk[2]; o.w = pk[3];
  *(uint4*)&((unsigned short*)sp)[j0] = o;
}

// ---------------- persistent bidirectional GRU ------------------------------
// 64 WGs: dir = wg>>5, slice = wg&31 owns 16 units. Waves 0-2 = gates r,z,n
// MFMA (16 wfrag = 64 VGPRs each, register-resident). Waves 0-1 = producers
// (batches 0-3 / 4-7): publish packed h dwords -> per-WAVE vmcnt(0) ack ->
// lane0 stores that wave's flag (no barrier). Consumers: every thread polls
// exactly ONE flag (the wave covering its 32B region), then loads 8 dwords.
// 2 barriers/step (B1 h-in-LDS, B2 ghbuf). Distance-2 phase safety as R2.
__global__ __launch_bounds__(256, 2)
void gru_kernel(const unsigned short* __restrict__ xw_f,
                const unsigned short* __restrict__ xw_b,
                const unsigned short* __restrict__ Whh_f,
                const unsigned short* __restrict__ Whh_b,
                const float* __restrict__ bhh_f,
                const float* __restrict__ bhh_b,
                unsigned short* __restrict__ hcat,
                unsigned int* __restrict__ hstate,  // [2 dir][2 phase][2048 dw]
                unsigned int* __restrict__ flags) { // [2dir][32sl][2wv][8 pad]
  const int wg = blockIdx.x;
  const int dir = wg >> 5;
  const int slice = wg & 31;
  const int u0 = slice << 4;
  const unsigned short* __restrict__ xwp = dir ? xw_b : xw_f;
  const unsigned short* __restrict__ Whh = dir ? Whh_b : Whh_f;
  const float* __restrict__ bhh = dir ? bhh_b : bhh_f;
  unsigned int* hstD = hstate + dir * 2 * 2048;
  unsigned int* flagD = flags + dir * 32 * 2 * 8;

  __shared__ __attribute__((aligned(16))) unsigned short hbf[16 * 552];
  __shared__ float ghbuf[3 * 128];

  const int tid = threadIdx.x;
  const int w = tid >> 6, l = tid & 63;
  const int fr = l & 15, fk = (l >> 4) << 3;

  for (int i = tid; i < 16 * 552; i += 256) hbf[i] = 0;

  bfx8 wfrag[16];
  if (w < 3) {
    const int grow = (w << 9) + u0 + fr;  // gate*512 + unit
#pragma unroll
    for (int ks = 0; ks < 16; ++ks)
      wfrag[ks] = *(const bfx8*)&Whh[(size_t)grow * 512 + (ks << 5) + fk];
  }
  const int b_ = tid >> 4, uu_ = tid & 15;
  float bh0 = 0.f, bh1 = 0.f, bh2 = 0.f;
  if (tid < 128) {
    bh0 = bhh[u0 + uu_];
    bh1 = bhh[512 + u0 + uu_];
    bh2 = bhh[1024 + u0 + uu_];
  }
  __syncthreads();  // hbf zeroed (h_0 = 0)

  float xr = 0.f, xz = 0.f, xn = 0.f;
  if (tid < 128) {
    int ta = dir ? 2047 : 0;
    size_t rb = (size_t)(b_ * 2048 + ta) * 1536;
    xr = bf2f(xwp[rb + u0 + uu_]);
    xz = bf2f(xwp[rb + 512 + u0 + uu_]);
    xn = bf2f(xwp[rb + 1024 + u0 + uu_]);
  }

  // consumer mapping: thread owns region (cb, s): 8 dwords = 16 units
  const int cb = tid >> 5;               // batch row 0..7
  const int cs = tid & 31;               // producer WG slice
  const unsigned int* const fp = &flagD[((cs << 1) + (cb >> 2)) << 3];
  unsigned int* const dstl = (unsigned int*)&hbf[cb * 552 + (cs << 4)];

  for (int t = 0; t < 2048; ++t) {
    const int t_act = dir ? (2047 - t) : t;
    // ---- per-thread: poll own region's flag, then load it (no barrier) ----
    if (t > 0) {
      while (__hip_atomic_load(fp, __ATOMIC_RELAXED, __HIP_MEMORY_SCOPE_AGENT)
             < (unsigned int)t) {}
      const unsigned int* hr = hstD + (t & 1) * 2048 + (cb << 8) + (cs << 3);
      unsigned int v0 = __hip_atomic_load(hr + 0, __ATOMIC_RELAXED, __HIP_MEMORY_SCOPE_AGENT);
      unsigned int v1 = __hip_atomic_load(hr + 1, __ATOMIC_RELAXED, __HIP_MEMORY_SCOPE_AGENT);
      unsigned int v2 = __hip_atomic_load(hr + 2, __ATOMIC_RELAXED, __HIP_MEMORY_SCOPE_AGENT);
      unsigned int v3 = __hip_atomic_load(hr + 3, __ATOMIC_RELAXED, __HIP_MEMORY_SCOPE_AGENT);
      unsigned int v4 = __hip_atomic_load(hr + 4, __ATOMIC_RELAXED, __HIP_MEMORY_SCOPE_AGENT);
      unsigned int v5 = __hip_atomic_load(hr + 5, __ATOMIC_RELAXED, __HIP_MEMORY_SCOPE_AGENT);
      unsigned int v6 = __hip_atomic_load(hr + 6, __ATOMIC_RELAXED, __HIP_MEMORY_SCOPE_AGENT);
      unsigned int v7 = __hip_atomic_load(hr + 7, __ATOMIC_RELAXED, __HIP_MEMORY_SCOPE_AGENT);
      dstl[0] = v0; dstl[1] = v1; dstl[2] = v2; dstl[3] = v3;
      dstl[4] = v4; dstl[5] = v5; dstl[6] = v6; dstl[7] = v7;
    }
    __syncthreads();  // B1: h_t in LDS
    if (w < 3) {
      fx4 z4 = {0.f, 0.f, 0.f, 0.f};
      fx4 acc0 = z4, acc1 = z4;
#pragma unroll
      for (int ks = 0; ks < 16; ks += 2) {
        bfx8 a0 = *(const bfx8*)&hbf[fr * 552 + (ks << 5) + fk];
        bfx8 a1 = *(const bfx8*)&hbf[fr * 552 + ((ks + 1) << 5) + fk];
        acc0 = __builtin_amdgcn_mfma_f32_16x16x32_bf16(a0, wfrag[ks], acc0, 0, 0, 0);
        acc1 = __builtin_amdgcn_mfma_f32_16x16x32_bf16(a1, wfrag[ks + 1], acc1, 0, 0, 0);
      }
      if (l < 32) {
#pragma unroll
        for (int i = 0; i < 4; ++i) {
          int bb = ((l >> 4) << 2) + i;  // batch row 0..7
          ghbuf[(w << 7) + (bb << 4) + fr] = acc0[i] + acc1[i];
        }
      }
    }
    __syncthreads();  // B2: ghbuf ready; hbf consumed by MFMA
    if (tid < 128) {
      float ghr = ghbuf[tid] + bh0;
      float ghz = ghbuf[128 + tid] + bh1;
      float ghn = ghbuf[256 + tid] + bh2;
      float r = 1.f / (1.f + __expf(-(xr + ghr)));
      float z = 1.f / (1.f + __expf(-(xz + ghz)));
      float n = tanhf(xn + r * ghn);
      float hprev = bf2f(hbf[b_ * 552 + u0 + uu_]);
      float hn = (1.f - z) * n + z * hprev;
      unsigned short hnb = f2bf(hn);
      unsigned int partner = (unsigned int)__shfl_down((int)hnb, 1);
      // publish packed h_{t+1} (even lanes), per-wave ack, lane0 flag
      if (t + 1 < 2048) {
        if (!(uu_ & 1)) {
          unsigned int pv = (unsigned int)hnb | (partner << 16);
          __hip_atomic_store(
              &hstD[((t + 1) & 1) * 2048 + (b_ << 8) + ((u0 + uu_) >> 1)], pv,
              __ATOMIC_RELAXED, __HIP_MEMORY_SCOPE_AGENT);
        }
        asm volatile("s_waitcnt vmcnt(0)" ::: "memory");  // this wave's stores
        if (l == 0)
          __hip_atomic_store((unsigned int*)&flagD[((slice << 1) + w) << 3],
                             (unsigned int)(t + 1),
                             __ATOMIC_RELAXED, __HIP_MEMORY_SCOPE_AGENT);
      }
      // tail (off critical path): hcat store + next xw prefetch
      hcat[((size_t)(b_ * 2048 + t_act) << 10) + (dir << 9) + u0 + uu_] = hnb;
      if (t + 1 < 2048) {
        int ta = dir ? (2046 - t) : (t + 1);
        size_t rb = (size_t)(b_ * 2048 + ta) * 1536;
        xr = bf2f(xwp[rb + u0 + uu_]);
        xz = bf2f(xwp[rb + 512 + u0 + uu_]);
        xn = bf2f(xwp[rb + 1024 + u0 + uu_]);
      }
    }
  }
}

// ---------------------------------------------------------------------------
extern "C" void kernel_launch(void* const* d_in, const int* in_sizes, int n_in,
                              void* d_out, int out_size, void* d_ws, size_t ws_size,
                              hipStream_t stream) {
  (void)in_sizes; (void)n_in; (void)out_size;
  const float* x    = (const float*)d_in[0];
  const float* W    = (const float*)d_in[1];
  const float* Wg   = (const float*)d_in[2];
  const float* Wihf = (const float*)d_in[3];
  const float* Whhf = (const float*)d_in[4];
  const float* bihf = (const float*)d_in[5];
  const float* bhhf = (const float*)d_in[6];
  const float* Wihb = (const float*)d_in[7];
  const float* Whhb = (const float*)d_in[8];
  const float* bihb = (const float*)d_in[9];
  const float* bhhb = (const float*)d_in[10];
  const float* Wp   = (const float*)d_in[11];
  const float* bp   = (const float*)d_in[12];
  float* out = (float*)d_out;

  char* base = (char*)d_ws;
  size_t off = 0;
  auto alloc = [&](size_t b) { void* r = base + off; off += (b + 255) & ~(size_t)255; return r; };
  unsigned short* xT   = (unsigned short*)alloc(8ull * 512 * 2048 * 2);
  unsigned short* xwf  = (unsigned short*)alloc(16384ull * 1536 * 2);
  unsigned short* xwb  = (unsigned short*)alloc(16384ull * 1536 * 2);
  unsigned short* rin  = (unsigned short*)alloc(16384ull * 1024 * 2);
  unsigned short* ring = (unsigned short*)alloc(16384ull * 1024 * 2);
  unsigned short* wW   = (unsigned short*)alloc(512ull * 512 * 2);
  unsigned short* wWg  = (unsigned short*)alloc(1024ull * 1024 * 2);
  unsigned short* wIf  = (unsigned short*)alloc(1536ull * 1024 * 2);
  unsigned short* wHf  = (unsigned short*)alloc(1536ull * 512 * 2);
  unsigned short* wIb  = (unsigned short*)alloc(1536ull * 1024 * 2);
  unsigned short* wHb  = (unsigned short*)alloc(1536ull * 512 * 2);
  unsigned short* wP   = (unsigned short*)alloc(512ull * 1024 * 2);
  unsigned int*   hst  = (unsigned int*)alloc(2ull * 2 * 2048 * 4);
  unsigned int*   flg  = (unsigned int*)alloc(2ull * 32 * 2 * 8 * 4);
  // overlays (lifetimes disjoint):
  float* sbuf = (float*)xwf;           // s scores, dead before xw_f written
  unsigned short* wxbf = ring;         // Wx, dead before ring written
  unsigned short* hcat = rin;          // GRU output, written after rin dead
  if (off > ws_size) return;           // fail loudly (output stays poisoned)

  (void)hipMemsetAsync(hst, 0, 2 * 2 * 2048 * 4, stream);
  (void)hipMemsetAsync(flg, 0, 2 * 32 * 2 * 8 * 4, stream);

  // weight casts
  cast_w_kernel<<<256,  256, 0, stream>>>(W,    wW,  512 * 512);
  cast_w_kernel<<<1024, 256, 0, stream>>>(Wg,   wWg, 1024 * 1024);
  cast_w_kernel<<<1536, 256, 0, stream>>>(Wihf, wIf, 1536 * 1024);
  cast_w_kernel<<<768,  256, 0, stream>>>(Whhf, wHf, 1536 * 512);
  cast_w_kernel<<<1536, 256, 0, stream>>>(Wihb, wIb, 1536 * 1024);
  cast_w_kernel<<<768,  256, 0, stream>>>(Whhb, wHb, 1536 * 512);
  cast_w_kernel<<<512,  256, 0, stream>>>(Wp,   wP,  512 * 1024);

  cast_x_kernel<<<8192, 256, 0, stream>>>(x, rin);
  transpose_kernel<<<dim3(32, 8, 8), 256, 0, stream>>>(x, xT);

  // Wx = x @ W^T  (A = rin left half)
  gemm_bt<EP_BF16><<<dim3(4, 128), 256, 0, stream>>>(rin, 1024, wW, 512, wxbf, 512, 512, nullptr, nullptr);

  // attention per batch: s -> softmax -> c (into rin[:,512:])
  for (int b = 0; b < 8; ++b) {
    gemm_bt<EP_F32><<<dim3(16, 16), 256, 0, stream>>>(
        wxbf + (size_t)b * 2048 * 512, 512, rin + (size_t)b * 2048 * 1024, 1024,
        sbuf, 2048, 512, nullptr, nullptr);
    softmax_kernel<<<2048, 256, 0, stream>>>(sbuf);
    gemm_bt<EP_BF16><<<dim3(4, 16), 256, 0, stream>>>(
        (const unsigned short*)sbuf, 4096, xT + (size_t)b * 512 * 2048, 2048,
        rin + (size_t)b * 2048 * 1024 + 512, 1024, 2048, nullptr, nullptr);
  }

  // gated concat: ring = rin * sigmoid(rin @ Wg^T)
  gemm_bt<EP_GATE><<<dim3(8, 128), 256, 0, stream>>>(rin, 1024, wWg, 1024, ring, 1024, 1024, rin, nullptr);

  // GRU input gates
  gemm_bt<EP_BIASBF><<<dim3(12, 128), 256, 0, stream>>>(ring, 1024, wIf, 1024, xwf, 1536, 1024, nullptr, bihf);
  gemm_bt<EP_BIASBF><<<dim3(12, 128), 256, 0, stream>>>(ring, 1024, wIb, 1024, xwb, 1536, 1024, nullptr, bihb);

  // persistent bidirectional GRU scan (writes hcat over rin region)
  gru_kernel<<<64, 256, 0, stream>>>(xwf, xwb, wHf, wHb, bhhf, bhhb, hcat, hst, flg);

  // out = x + hcat @ Wp^T + bp
  gemm_bt<EP_RESID><<<dim3(4, 128), 256, 0, stream>>>(hcat, 1024, wP, 1024, out, 512, 1024, x, bp);
}